// Round 8
// baseline (1255.325 us; speedup 1.0000x reference)
//
#include <hip/hip_runtime.h>

typedef _Float16 half8 __attribute__((ext_vector_type(8)));
typedef float floatx16 __attribute__((ext_vector_type(16)));
typedef float float4v __attribute__((ext_vector_type(4)));

#define MTOT 131072   // B*T rows
#define DDIM 1024
#define TLEN 4096
#define BATCH 32
#define NMASK 2048

__device__ __forceinline__ void gll16f(const float* g, const float* l) {
  __builtin_amdgcn_global_load_lds(
      (const __attribute__((address_space(1))) void*)g,
      (__attribute__((address_space(3))) void*)l, 16, 0, 0);
}

// --------- kernel 0: pack W1 into MFMA B-fragment order, fp16-split (x512) ----
// 2048 fragments: f = cb*64 + kb. Wp[f][hl][lane][8]: lane l -> col cb*32+(l&31),
// k kb*16+(l>>5)*8+j. B-frag load in k_score = ONE coalesced 1KB wave-load.
__global__ void k_wpack(const float* __restrict__ W1, _Float16* __restrict__ Wp)
{
  const int f = blockIdx.x * 4 + (threadIdx.x >> 6);  // 0..2047
  const int l = threadIdx.x & 63;
  const int cb = f >> 6, kb = f & 63;
  const int col = cb * 32 + (l & 31);
  const int k0 = kb * 16 + (l >> 5) * 8;
  half8 hv, lv;
#pragma unroll
  for (int j = 0; j < 8; j++) {
    float w = W1[(size_t)(k0 + j) * DDIM + col] * 512.0f;
    _Float16 h = (_Float16)w;
    hv[j] = h; lv[j] = (_Float16)(w - (float)h);
  }
  *(half8*)(Wp + ((size_t)(f * 2 + 0) * 64 + l) * 8) = hv;
  *(half8*)(Wp + ((size_t)(f * 2 + 1) * 64 + l) * 8) = lv;
}

// --------- kernel 1: fused scores GEMM ----------------------------------------
// tile 128x256, 8 waves (2x4), wave 64x64 = 2x2 frags of mfma_f32_32x32x16_f16.
// ONE barrier per K-tile; VMEM queue age-ordered: [16 B(t)] [4 gll A(t+1)]
// [4x(ds_read fp32 + reg split + 12 MFMA)] [sync]. B-waits keep glls in flight
// (in-order retirement); barrier vmcnt(0) drain hits >=1536cyc-old glls = free.
// A staged as raw fp32 via gll, chunk-XOR swizzled at the SOURCE (c ^= r&15),
// un-swizzled on ds_read; hi/lo f16 split in regs (VALU co-issues with MFMA).
__global__ __launch_bounds__(512, 2) void k_score(
    const float* __restrict__ x, const _Float16* __restrict__ Wp,
    const float* __restrict__ b1, const float* __restrict__ w2,
    float* __restrict__ partials)
{
  __shared__ __align__(16) float Abuf[2][128 * 64];   // 32 KB per buffer
  __shared__ float part_lds[4][128];

  const int tid  = threadIdx.x;
  const int lane = tid & 63;
  const int wave = tid >> 6;
  const int wr = wave >> 2, wn = wave & 3;
  const int l31 = lane & 31, l5 = lane >> 5;

  // XCD-bijective decode (proven FETCH-halving): 4 col-blocks of a row-panel
  // land on one XCD -> panel enters that L2 once.
  const int id  = blockIdx.x;
  const int xcd = id & 7, seq = id >> 3;
  const int px  = seq & 3;                 // col-block 0..3
  const int py  = (seq >> 2) * 8 + xcd;    // row-panel 0..1023
  const int m0 = py * 128;

  // gll q of wave w: lane l -> LDS row r=(w*4+q)*4+(l>>4), phys 16B-chunk c=l&15.
  // Phys chunk c must hold logical chunk c^(r&15) -> pre-swizzle the source.
  const float* gsrc[4];
#pragma unroll
  for (int q = 0; q < 4; q++) {
    int r = (wave * 4 + q) * 4 + (lane >> 4);
    int c = lane & 15;
    gsrc[q] = x + (size_t)(m0 + r) * DDIM + ((c ^ (r & 15)) * 4);
  }

  // B fragment bases (per nf): frag index (t*4+kc) within col-block cb
  const _Float16* wpb[2];
#pragma unroll
  for (int nf = 0; nf < 2; nf++)
    wpb[nf] = Wp + (size_t)((px * 8 + wn * 2 + nf) * 64) * 1024 + lane * 8;

  floatx16 acc[2][2] = {};

  // ---- prologue: gll tile 0 -> buf 0 ----
#pragma unroll
  for (int q = 0; q < 4; q++)
    gll16f(gsrc[q], &Abuf[0][(wave * 4 + q) * 256]);
  __syncthreads();

#pragma unroll 1
  for (int t = 0; t < 16; ++t) {
    const int cur = t & 1;
    // ---- oldest: all 16 B(t) fragment-halves (coalesced 1KB wave-loads) ----
    half8 b[4][2][2];                      // [kc][nf][hi/lo], static-indexed
#pragma unroll
    for (int kc = 0; kc < 4; kc++)
#pragma unroll
      for (int nf = 0; nf < 2; nf++) {
        b[kc][nf][0] = *(const half8*)(wpb[nf] + (size_t)(t * 4 + kc) * 1024);
        b[kc][nf][1] = *(const half8*)(wpb[nf] + (size_t)(t * 4 + kc) * 1024 + 512);
      }
    // ---- youngest VMEM: stage A(t+1); stays in flight through all MFMA ----
    if (t < 15) {
#pragma unroll
      for (int q = 0; q < 4; q++)
        gll16f(gsrc[q] + (t + 1) * 64, &Abuf[cur ^ 1][(wave * 4 + q) * 256]);
    }
    // ---- compute: per kc, ds_read fp32 frag -> split -> 12 MFMA ----
#pragma unroll
    for (int kc = 0; kc < 4; kc++) {
      half8 ah[2], al[2];
#pragma unroll
      for (int mf = 0; mf < 2; mf++) {
        int r  = wr * 64 + mf * 32 + l31;
        int c0 = kc * 4 + l5 * 2;
        float4v f0 = *(const float4v*)&Abuf[cur][r * 64 + ((c0    ) ^ (r & 15)) * 4];
        float4v f1 = *(const float4v*)&Abuf[cur][r * 64 + ((c0 + 1) ^ (r & 15)) * 4];
#pragma unroll
        for (int i = 0; i < 4; i++) {
          _Float16 h0 = (_Float16)f0[i];
          ah[mf][i] = h0; al[mf][i] = (_Float16)(f0[i] - (float)h0);
          _Float16 h1 = (_Float16)f1[i];
          ah[mf][4 + i] = h1; al[mf][4 + i] = (_Float16)(f1[i] - (float)h1);
        }
      }
#pragma unroll
      for (int mf = 0; mf < 2; mf++)
#pragma unroll
        for (int nf = 0; nf < 2; nf++) {
          acc[mf][nf] = __builtin_amdgcn_mfma_f32_32x32x16_f16(ah[mf], b[kc][nf][0], acc[mf][nf], 0, 0, 0);
          acc[mf][nf] = __builtin_amdgcn_mfma_f32_32x32x16_f16(ah[mf], b[kc][nf][1], acc[mf][nf], 0, 0, 0);
          acc[mf][nf] = __builtin_amdgcn_mfma_f32_32x32x16_f16(al[mf], b[kc][nf][0], acc[mf][nf], 0, 0, 0);
        }
    }
    __syncthreads();   // drains only >=1536cyc-old glls; flips dbuf
  }

  // ---- epilogue: tanh + dot(w2) + row reduce ----
  float b1v[2], w2v[2];
#pragma unroll
  for (int nf = 0; nf < 2; nf++) {
    int col = px * 256 + wn * 64 + nf * 32 + l31;
    b1v[nf] = b1[col];
    w2v[nf] = w2[col];
  }
  const float inv512 = 1.0f / 512.0f;
#pragma unroll
  for (int mf = 0; mf < 2; mf++)
#pragma unroll
    for (int reg = 0; reg < 16; reg++) {
      float s = 0.0f;
#pragma unroll
      for (int nf = 0; nf < 2; nf++) {
        float pre = acc[mf][nf][reg] * inv512 + b1v[nf];
        float a = fabsf(pre);
        float e = __expf(-2.0f * a);
        float t = (1.0f - e) / (1.0f + e);            // tanh(|pre|)
        s += copysignf(t, pre) * w2v[nf];
      }
#pragma unroll
      for (int off = 1; off < 32; off <<= 1) s += __shfl_xor(s, off, 64);
      if (l31 == 0)
        part_lds[wn][wr * 64 + mf * 32 + (reg & 3) + 8 * (reg >> 2) + 4 * l5] = s;
    }
  __syncthreads();
  if (tid < 128) {
    float v = part_lds[0][tid] + part_lds[1][tid] + part_lds[2][tid] + part_lds[3][tid];
    partials[(size_t)px * MTOT + m0 + tid] = v;
  }
}

// --------- kernel 2: per-batch-row exact select (stable-argsort semantics) + softmax
__global__ void k_select(const float* __restrict__ partials, const float* __restrict__ b2,
                         float* __restrict__ weights)
{
  __shared__ float s_lds[TLEN];
  __shared__ unsigned long long keys[TLEN];
  __shared__ float red[20];
  const int b = blockIdx.x, tid = threadIdx.x;
  const float b2v = b2[0];

  for (int i = tid; i < TLEN; i += 1024) {
    size_t idx = (size_t)b * TLEN + i;
    float s = partials[idx] + partials[idx + (size_t)MTOT] +
              partials[idx + 2 * (size_t)MTOT] + partials[idx + 3 * (size_t)MTOT] + b2v;
    s_lds[i] = s;
    unsigned u = __float_as_uint(s);
    u = (u & 0x80000000u) ? ~u : (u | 0x80000000u);  // order-preserving float->uint
    keys[i] = ((unsigned long long)u << 32) | (unsigned)i;
  }
  __syncthreads();
  // bitonic sort ascending (key = (score, index) — matches stable argsort)
  for (int k = 2; k <= TLEN; k <<= 1)
    for (int j = k >> 1; j > 0; j >>= 1) {
      for (int i = tid; i < TLEN; i += 1024) {
        int p = i ^ j;
        if (p > i) {
          unsigned long long a = keys[i], c = keys[p];
          bool up = ((i & k) == 0);
          if ((a > c) == up) { keys[i] = c; keys[p] = a; }
        }
      }
      __syncthreads();
    }

  const unsigned long long thr = keys[NMASK];        // first KEPT pair
  unsigned um = (unsigned)(keys[TLEN - 1] >> 32);    // decode row max
  um = (um & 0x80000000u) ? (um ^ 0x80000000u) : ~um;
  const float m = __uint_as_float(um);

  float ev[4]; bool kp[4]; float zp = 0.0f;
#pragma unroll
  for (int q = 0; q < 4; q++) {
    int i = tid + q * 1024;
    float s = s_lds[i];
    unsigned u = __float_as_uint(s);
    u = (u & 0x80000000u) ? ~u : (u | 0x80000000u);
    unsigned long long key = ((unsigned long long)u << 32) | (unsigned)i;
    kp[q] = (key >= thr);
    ev[q] = __expf(s - m);
    if (kp[q]) zp += ev[q];
  }
#pragma unroll
  for (int off = 1; off < 64; off <<= 1) zp += __shfl_xor(zp, off, 64);
  if ((tid & 63) == 0) red[tid >> 6] = zp;
  __syncthreads();
  if (tid == 0) { float z = 0.0f; for (int i = 0; i < 16; i++) z += red[i]; red[16] = z; }
  __syncthreads();
  const float invZ = 1.0f / red[16];
#pragma unroll
  for (int q = 0; q < 4; q++) {
    int i = tid + q * 1024;
    weights[(size_t)b * TLEN + i] = kp[q] ? ev[q] * invZ : 0.0f;
  }
}

// --------- kernel 3: masked_output = x * weights[row] ---------
__global__ void k_scale(const float* __restrict__ x, const float* __restrict__ weights,
                        float* __restrict__ out)
{
  const size_t n4 = (size_t)MTOT * DDIM / 4;
  for (size_t f = (size_t)blockIdx.x * blockDim.x + threadIdx.x; f < n4;
       f += (size_t)gridDim.x * blockDim.x) {
    float w = weights[f >> 8];                       // 256 float4 per row
    float4v v = ((const float4v*)x)[f];
    ((float4v*)out)[f] = v * w;
  }
}

extern "C" void kernel_launch(void* const* d_in, const int* in_sizes, int n_in,
                              void* d_out, int out_size, void* d_ws, size_t ws_size,
                              hipStream_t stream)
{
  const float* x  = (const float*)d_in[0];
  const float* W1 = (const float*)d_in[1];
  const float* b1 = (const float*)d_in[2];
  const float* w2 = (const float*)d_in[3];
  const float* b2 = (const float*)d_in[4];
  float* out = (float*)d_out;
  float* weights = out + (size_t)MTOT * DDIM;        // output 1 region

  // Wp (8 MiB) lives in d_out's masked_output region (dead until k_scale
  // overwrites it at the very end — proven-safe scratch in R4-R7).
  _Float16* Wp = (_Float16*)d_out;
  float* parts = (float*)d_ws;                       // 2 MiB

  k_wpack<<<512, 256, 0, stream>>>(W1, Wp);          // 2048 frags x 4/block
  k_score<<<4096, 512, 0, stream>>>(x, Wp, b1, w2, parts);
  k_select<<<BATCH, 1024, 0, stream>>>(parts, b2, weights);
  k_scale<<<2048, 256, 0, stream>>>(x, weights, out);
}

// Round 9
// 1234.152 us; speedup vs baseline: 1.0172x; 1.0172x over previous
//
#include <hip/hip_runtime.h>

typedef _Float16 half8 __attribute__((ext_vector_type(8)));
typedef float floatx16 __attribute__((ext_vector_type(16)));
typedef float float4v __attribute__((ext_vector_type(4)));

#define MTOT 131072   // B*T rows
#define DDIM 1024
#define TLEN 4096
#define BATCH 32
#define NMASK 2048

__device__ __forceinline__ void gll16h(const _Float16* g, const _Float16* l) {
  __builtin_amdgcn_global_load_lds(
      (const __attribute__((address_space(1))) void*)g,
      (__attribute__((address_space(3))) void*)l, 16, 0, 0);
}

// --------- kernel 0: pack W1 into MFMA B-fragment order, fp16-split (x512) ----
// 2048 fragments: f = cb*64 + kb. Wp[f][hl][lane][8]: lane l -> col cb*32+(l&31),
// k kb*16+(l>>5)*8+j. B-frag load in k_score = ONE coalesced 1KB wave-load.
__global__ void k_wpack(const float* __restrict__ W1, _Float16* __restrict__ Wp)
{
  const int f = blockIdx.x * 4 + (threadIdx.x >> 6);  // 0..2047
  const int l = threadIdx.x & 63;
  const int cb = f >> 6, kb = f & 63;
  const int col = cb * 32 + (l & 31);
  const int k0 = kb * 16 + (l >> 5) * 8;
  half8 hv, lv;
#pragma unroll
  for (int j = 0; j < 8; j++) {
    float w = W1[(size_t)(k0 + j) * DDIM + col] * 512.0f;
    _Float16 h = (_Float16)w;
    hv[j] = h; lv[j] = (_Float16)(w - (float)h);
  }
  *(half8*)(Wp + ((size_t)(f * 2 + 0) * 64 + l) * 8) = hv;
  *(half8*)(Wp + ((size_t)(f * 2 + 1) * 64 + l) * 8) = lv;
}

// --------- kernel 0b: fp16-split x into interleaved tile layout ---------------
// xhl[row][t][0..63] = hi f16 of x[row][t*64..+63]; [64..127] = lo f16.
// Same bytes/elem as fp32 (4B) -> k_score FETCH unchanged; split VALU leaves
// the GEMM loop entirely.
__global__ void k_xsplit(const float* __restrict__ x, _Float16* __restrict__ xhl)
{
  const size_t ngroups = (size_t)MTOT * 128;           // 8-elem groups
  for (size_t i = (size_t)blockIdx.x * 256 + threadIdx.x; i < ngroups;
       i += (size_t)gridDim.x * 256) {
    size_t row = i >> 7; int g = (int)(i & 127);
    int t = g >> 3, c = g & 7;
    const float* src = x + row * DDIM + t * 64 + c * 8;
    float4v v0 = *(const float4v*)src;
    float4v v1 = *(const float4v*)(src + 4);
    half8 hv, lv;
#pragma unroll
    for (int j = 0; j < 4; j++) {
      _Float16 h0 = (_Float16)v0[j];
      hv[j] = h0;     lv[j] = (_Float16)(v0[j] - (float)h0);
      _Float16 h1 = (_Float16)v1[j];
      hv[4 + j] = h1; lv[4 + j] = (_Float16)(v1[j] - (float)h1);
    }
    _Float16* dst = xhl + row * 2048 + t * 128;
    *(half8*)(dst + c * 8) = hv;
    *(half8*)(dst + 64 + c * 8) = lv;
  }
}

// --------- kernel 1: fused scores GEMM ----------------------------------------
// tile 128x256, 8 waves COL-SPLIT (wave wn owns cols wn*32, all 128 rows:
// 4 mf frags of 32x32x16, acc 64 regs). No B duplication across waves.
// Per t: [8 B(t) loads oldest][4 gll A(t+1) youngest][4 kc x (8 ds_read_b128 +
// 12 MFMA)][ONE barrier]. No split VALU in loop (prepass). Source-XOR swizzle
// c^=(r&15) on 256B rows -> 2-way (free) ds_reads. launch_bounds(512,4):
// target <=128 regs -> 2 blocks/CU, 4 waves/SIMD.
__global__ __launch_bounds__(512, 4) void k_score(
    const _Float16* __restrict__ xhl, const _Float16* __restrict__ Wp,
    const float* __restrict__ b1, const float* __restrict__ w2,
    float* __restrict__ partials)
{
  __shared__ __align__(16) _Float16 Abuf[2][128 * 128];  // 32 KB each
  __shared__ float part_lds[8][128];

  const int tid  = threadIdx.x;
  const int lane = tid & 63;
  const int wn   = tid >> 6;               // wave = col group 0..7
  const int l31 = lane & 31, l5 = lane >> 5;

  // XCD-bijective decode (proven FETCH-halving): 4 col-blocks of a row-panel
  // land on one XCD -> panel enters that L2 once.
  const int id  = blockIdx.x;
  const int xcd = id & 7, seq = id >> 3;
  const int px  = seq & 3;                 // col-block 0..3
  const int py  = (seq >> 2) * 8 + xcd;    // row-panel 0..1023
  const int m0 = py * 128;

  // gll q of wave wn: unit u = (wn*4+q)*64 + lane; row r=u>>4, phys chunk c=u&15
  // holds logical chunk c^(r&15) -> pre-swizzle the global source.
  const _Float16* gsrc[4];
#pragma unroll
  for (int q = 0; q < 4; q++) {
    int u = (wn * 4 + q) * 64 + lane;
    int r = u >> 4, c = u & 15;
    gsrc[q] = xhl + (size_t)(m0 + r) * 2048 + ((c ^ (r & 15)) * 8);
  }

  // B fragment base: col-group cb = px*8 + wn; frag (cb*64 + t*4 + kc)
  const _Float16* wpb = Wp + (size_t)(px * 8 + wn) * 64 * 1024 + lane * 8;

  floatx16 acc[4] = {};

  // ---- prologue: gll tile 0 -> buf 0 ----
#pragma unroll
  for (int q = 0; q < 4; q++)
    gll16h(gsrc[q], &Abuf[0][(wn * 4 + q) * 512]);
  __syncthreads();

#pragma unroll 1
  for (int t = 0; t < 16; ++t) {
    const int cur = t & 1;
    // ---- oldest VMEM: this tile's 8 B-halves (coalesced 1KB wave-loads) ----
    half8 bh[4], bl[4];
#pragma unroll
    for (int kc = 0; kc < 4; kc++) {
      bh[kc] = *(const half8*)(wpb + (size_t)(t * 4 + kc) * 1024);
      bl[kc] = *(const half8*)(wpb + (size_t)(t * 4 + kc) * 1024 + 512);
    }
    // ---- youngest VMEM: stage A(t+1); in flight through all MFMA ----
    if (t < 15) {
#pragma unroll
      for (int q = 0; q < 4; q++)
        gll16h(gsrc[q] + (t + 1) * 128, &Abuf[cur ^ 1][(wn * 4 + q) * 512]);
    }
    // ---- compute ----
#pragma unroll
    for (int kc = 0; kc < 4; kc++) {
#pragma unroll
      for (int mf = 0; mf < 4; mf++) {
        int r = mf * 32 + l31;
        int base = r * 128;
        half8 ah = *(const half8*)&Abuf[cur][base + (((kc * 2 + l5)    ) ^ (r & 15)) * 8];
        half8 al = *(const half8*)&Abuf[cur][base + ((8 + kc * 2 + l5) ^ (r & 15)) * 8];
        acc[mf] = __builtin_amdgcn_mfma_f32_32x32x16_f16(ah, bh[kc], acc[mf], 0, 0, 0);
        acc[mf] = __builtin_amdgcn_mfma_f32_32x32x16_f16(ah, bl[kc], acc[mf], 0, 0, 0);
        acc[mf] = __builtin_amdgcn_mfma_f32_32x32x16_f16(al, bh[kc], acc[mf], 0, 0, 0);
      }
    }
    __syncthreads();   // drains only >=1500cyc-old VMEM; flips dbuf
  }

  // ---- epilogue: tanh + dot(w2) + row reduce (32 cols per wave) ----
  const int col = px * 256 + wn * 32 + l31;
  const float b1v = b1[col];
  const float w2v = w2[col];
  const float inv512 = 1.0f / 512.0f;
#pragma unroll
  for (int mf = 0; mf < 4; mf++)
#pragma unroll
    for (int reg = 0; reg < 16; reg++) {
      float pre = acc[mf][reg] * inv512 + b1v;
      float a = fabsf(pre);
      float e = __expf(-2.0f * a);
      float tt = (1.0f - e) / (1.0f + e);             // tanh(|pre|)
      float s = copysignf(tt, pre) * w2v;
#pragma unroll
      for (int off = 1; off < 32; off <<= 1) s += __shfl_xor(s, off, 64);
      if (l31 == 0)
        part_lds[wn][mf * 32 + (reg & 3) + 8 * (reg >> 2) + 4 * l5] = s;
    }
  __syncthreads();
  if (tid < 128) {
    float v = 0.0f;
#pragma unroll
    for (int w = 0; w < 8; w++) v += part_lds[w][tid];
    partials[(size_t)px * MTOT + m0 + tid] = v;
  }
}

// --------- kernel 2: per-batch-row exact select (stable-argsort semantics) + softmax
__global__ void k_select(const float* __restrict__ partials, const float* __restrict__ b2,
                         float* __restrict__ weights)
{
  __shared__ float s_lds[TLEN];
  __shared__ unsigned long long keys[TLEN];
  __shared__ float red[20];
  const int b = blockIdx.x, tid = threadIdx.x;
  const float b2v = b2[0];

  for (int i = tid; i < TLEN; i += 1024) {
    size_t idx = (size_t)b * TLEN + i;
    float s = partials[idx] + partials[idx + (size_t)MTOT] +
              partials[idx + 2 * (size_t)MTOT] + partials[idx + 3 * (size_t)MTOT] + b2v;
    s_lds[i] = s;
    unsigned u = __float_as_uint(s);
    u = (u & 0x80000000u) ? ~u : (u | 0x80000000u);  // order-preserving float->uint
    keys[i] = ((unsigned long long)u << 32) | (unsigned)i;
  }
  __syncthreads();
  // bitonic sort ascending (key = (score, index) — matches stable argsort)
  for (int k = 2; k <= TLEN; k <<= 1)
    for (int j = k >> 1; j > 0; j >>= 1) {
      for (int i = tid; i < TLEN; i += 1024) {
        int p = i ^ j;
        if (p > i) {
          unsigned long long a = keys[i], c = keys[p];
          bool up = ((i & k) == 0);
          if ((a > c) == up) { keys[i] = c; keys[p] = a; }
        }
      }
      __syncthreads();
    }

  const unsigned long long thr = keys[NMASK];        // first KEPT pair
  unsigned um = (unsigned)(keys[TLEN - 1] >> 32);    // decode row max
  um = (um & 0x80000000u) ? (um ^ 0x80000000u) : ~um;
  const float m = __uint_as_float(um);

  float ev[4]; bool kp[4]; float zp = 0.0f;
#pragma unroll
  for (int q = 0; q < 4; q++) {
    int i = tid + q * 1024;
    float s = s_lds[i];
    unsigned u = __float_as_uint(s);
    u = (u & 0x80000000u) ? ~u : (u | 0x80000000u);
    unsigned long long key = ((unsigned long long)u << 32) | (unsigned)i;
    kp[q] = (key >= thr);
    ev[q] = __expf(s - m);
    if (kp[q]) zp += ev[q];
  }
#pragma unroll
  for (int off = 1; off < 64; off <<= 1) zp += __shfl_xor(zp, off, 64);
  if ((tid & 63) == 0) red[tid >> 6] = zp;
  __syncthreads();
  if (tid == 0) { float z = 0.0f; for (int i = 0; i < 16; i++) z += red[i]; red[16] = z; }
  __syncthreads();
  const float invZ = 1.0f / red[16];
#pragma unroll
  for (int q = 0; q < 4; q++) {
    int i = tid + q * 1024;
    weights[(size_t)b * TLEN + i] = kp[q] ? ev[q] * invZ : 0.0f;
  }
}

// --------- kernel 3: masked_output = x * weights[row] ---------
__global__ void k_scale(const float* __restrict__ x, const float* __restrict__ weights,
                        float* __restrict__ out)
{
  const size_t n4 = (size_t)MTOT * DDIM / 4;
  for (size_t f = (size_t)blockIdx.x * blockDim.x + threadIdx.x; f < n4;
       f += (size_t)gridDim.x * blockDim.x) {
    float w = weights[f >> 8];                       // 256 float4 per row
    float4v v = ((const float4v*)x)[f];
    ((float4v*)out)[f] = v * w;
  }
}

extern "C" void kernel_launch(void* const* d_in, const int* in_sizes, int n_in,
                              void* d_out, int out_size, void* d_ws, size_t ws_size,
                              hipStream_t stream)
{
  const float* x  = (const float*)d_in[0];
  const float* W1 = (const float*)d_in[1];
  const float* b1 = (const float*)d_in[2];
  const float* w2 = (const float*)d_in[3];
  const float* b2 = (const float*)d_in[4];
  float* out = (float*)d_out;
  float* weights = out + (size_t)MTOT * DDIM;        // output 1 region

  // xhl (512 MiB) lives in d_out's masked_output region (dead until k_scale
  // overwrites it at the very end — proven-safe scratch R4-R8).
  _Float16* xhl = (_Float16*)d_out;

  char* ws = (char*)d_ws;                            // 6 MiB total (R1-R3 proven)
  _Float16* Wp   = (_Float16*)ws;                    // 4 MiB
  float*    parts = (float*)(ws + (4u << 20));       // 2 MiB

  k_wpack<<<512, 256, 0, stream>>>(W1, Wp);          // 2048 frags x 4/block
  k_xsplit<<<4096, 256, 0, stream>>>(x, xhl);
  k_score<<<4096, 512, 0, stream>>>(xhl, Wp, b1, w2, parts);
  k_select<<<BATCH, 1024, 0, stream>>>(parts, b2, weights);
  k_scale<<<2048, 256, 0, stream>>>(x, weights, out);
}

// Round 10
// 1147.340 us; speedup vs baseline: 1.0941x; 1.0757x over previous
//
#include <hip/hip_runtime.h>

typedef _Float16 half8 __attribute__((ext_vector_type(8)));
typedef _Float16 half4v __attribute__((ext_vector_type(4)));
typedef float floatx16 __attribute__((ext_vector_type(16)));
typedef float float4v __attribute__((ext_vector_type(4)));

#define MTOT 131072   // B*T rows
#define DDIM 1024
#define TLEN 4096
#define BATCH 32
#define NMASK 2048

// --------- kernel 0: pack W1 into MFMA B-fragment order, fp16-split (x512) ----
// 2048 fragments: f = cb*64 + kb. Wp[f][hl][lane][8]: lane l -> col cb*32+(l&31),
// k kb*16+(l>>5)*8+j. B-frag load in k_score = ONE coalesced 1KB wave-load.
__global__ void k_wpack(const float* __restrict__ W1, _Float16* __restrict__ Wp)
{
  const int f = blockIdx.x * 4 + (threadIdx.x >> 6);  // 0..2047
  const int l = threadIdx.x & 63;
  const int cb = f >> 6, kb = f & 63;
  const int col = cb * 32 + (l & 31);
  const int k0 = kb * 16 + (l >> 5) * 8;
  half8 hv, lv;
#pragma unroll
  for (int j = 0; j < 8; j++) {
    float w = W1[(size_t)(k0 + j) * DDIM + col] * 512.0f;
    _Float16 h = (_Float16)w;
    hv[j] = h; lv[j] = (_Float16)(w - (float)h);
  }
  *(half8*)(Wp + ((size_t)(f * 2 + 0) * 64 + l) * 8) = hv;
  *(half8*)(Wp + ((size_t)(f * 2 + 1) * 64 + l) * 8) = lv;
}

// --------- kernel 1: fused scores GEMM ----------------------------------------
// tile 128x256, 8 waves COL-SPLIT (wave wn owns cols wn*32, all 128 rows).
// A: reg-staged from x (fp32), split fp32->hi/lo f16 ONCE per block at LDS-write
// time (16 elems/thread/t), ds_write_b64 into the R9 hi||lo XOR layout
// (write phys chunk (c>>1)^(r&15); read side identical involution).
// Per t (age-monotone VMEM queue): [8 B(t) L2 loads][4 A(t+1) HBM loads,
// youngest][setprio(1) MFMA setprio(0)][sched_barrier][split+write: vmcnt hits
// A loads aged ~= full compute][ONE barrier].
__global__ __launch_bounds__(512, 4) void k_score(
    const float* __restrict__ x, const _Float16* __restrict__ Wp,
    const float* __restrict__ b1, const float* __restrict__ w2,
    float* __restrict__ partials)
{
  __shared__ __align__(16) _Float16 Abuf[2][128 * 128];  // 32 KB each
  __shared__ float part_lds[8][128];

  const int tid  = threadIdx.x;
  const int lane = tid & 63;
  const int wn   = tid >> 6;               // wave = col group 0..7
  const int l31 = lane & 31, l5 = lane >> 5;

  // XCD-bijective decode (proven FETCH-halving): 4 col-blocks of a row-panel
  // land on one XCD -> panel enters that L2 once.
  const int id  = blockIdx.x;
  const int xcd = id & 7, seq = id >> 3;
  const int px  = seq & 3;                 // col-block 0..3
  const int py  = (seq >> 2) * 8 + xcd;    // row-panel 0..1023
  const int m0 = py * 128;

  // A staging map: thread -> (row rr+g*32, f32-quad cc) ; coalesced 256B/16 lanes
  const int rr = tid >> 4;                 // 0..31
  const int cc = tid & 15;                 // f32-quad within 64
  const float* xs = x + (size_t)(m0 + rr) * DDIM + cc * 4;

  // B fragment base: col-group cb = px*8 + wn; frag (cb*64 + t*4 + kc)
  const _Float16* wpb = Wp + (size_t)(px * 8 + wn) * 64 * 1024 + lane * 8;

  floatx16 acc[4] = {};
  float4v xv[4];

#define LOADX(T)                                                        \
  _Pragma("unroll")                                                     \
  for (int g = 0; g < 4; g++)                                           \
    xv[g] = *(const float4v*)(xs + (size_t)g * 32 * DDIM + (T) * 64);

  // split 16 f32 -> hi/lo f16, write as 8B units into XOR'd chunk layout
#define SPLITW(BUF)                                                     \
  _Pragma("unroll")                                                     \
  for (int g = 0; g < 4; g++) {                                         \
    int r = rr + g * 32;                                                \
    int Phi = (cc >> 1) ^ (r & 15);                                     \
    half4v hv, lv;                                                      \
    _Pragma("unroll")                                                   \
    for (int i = 0; i < 4; i++) {                                       \
      _Float16 h = (_Float16)xv[g][i];                                  \
      hv[i] = h; lv[i] = (_Float16)(xv[g][i] - (float)h);               \
    }                                                                   \
    *(half4v*)&Abuf[BUF][r * 128 + Phi * 8 + (cc & 1) * 4] = hv;        \
    *(half4v*)&Abuf[BUF][r * 128 + (Phi ^ 8) * 8 + (cc & 1) * 4] = lv;  \
  }

  // ---- prologue: tile 0 -> buf 0 ----
  LOADX(0)
  SPLITW(0)
  __syncthreads();

#pragma unroll 1
  for (int t = 0; t < 16; ++t) {
    const int cur = t & 1;
    // ---- oldest VMEM: this tile's 8 B-halves (coalesced 1KB wave-loads) ----
    half8 bh[4], bl[4];
#pragma unroll
    for (int kc = 0; kc < 4; kc++) {
      bh[kc] = *(const half8*)(wpb + (size_t)(t * 4 + kc) * 1024);
      bl[kc] = *(const half8*)(wpb + (size_t)(t * 4 + kc) * 1024 + 512);
    }
    // ---- youngest VMEM: A(t+1) -> regs; in flight through all MFMA ----
    if (t < 15) LOADX(t + 1)
    __builtin_amdgcn_sched_barrier(0);
    __builtin_amdgcn_s_setprio(1);
#pragma unroll
    for (int kc = 0; kc < 4; kc++) {
#pragma unroll
      for (int mf = 0; mf < 4; mf++) {
        int r = mf * 32 + l31;
        int base = r * 128;
        half8 ah = *(const half8*)&Abuf[cur][base + (((kc * 2 + l5)    ) ^ (r & 15)) * 8];
        half8 al = *(const half8*)&Abuf[cur][base + ((8 + kc * 2 + l5) ^ (r & 15)) * 8];
        acc[mf] = __builtin_amdgcn_mfma_f32_32x32x16_f16(ah, bh[kc], acc[mf], 0, 0, 0);
        acc[mf] = __builtin_amdgcn_mfma_f32_32x32x16_f16(ah, bl[kc], acc[mf], 0, 0, 0);
        acc[mf] = __builtin_amdgcn_mfma_f32_32x32x16_f16(al, bh[kc], acc[mf], 0, 0, 0);
      }
    }
    __builtin_amdgcn_s_setprio(0);
    __builtin_amdgcn_sched_barrier(0);
    // ---- split+write A(t+1): vmcnt wait hits loads aged ~= whole compute ----
    if (t < 15) SPLITW(cur ^ 1)
    __syncthreads();
  }
#undef LOADX
#undef SPLITW

  // ---- epilogue: tanh + dot(w2) + row reduce (32 cols per wave) ----
  const int col = px * 256 + wn * 32 + l31;
  const float b1v = b1[col];
  const float w2v = w2[col];
  const float inv512 = 1.0f / 512.0f;
#pragma unroll
  for (int mf = 0; mf < 4; mf++)
#pragma unroll
    for (int reg = 0; reg < 16; reg++) {
      float pre = acc[mf][reg] * inv512 + b1v;
      float a = fabsf(pre);
      float e = __expf(-2.0f * a);
      float tt = (1.0f - e) / (1.0f + e);             // tanh(|pre|)
      float s = copysignf(tt, pre) * w2v;
#pragma unroll
      for (int off = 1; off < 32; off <<= 1) s += __shfl_xor(s, off, 64);
      if (l31 == 0)
        part_lds[wn][mf * 32 + (reg & 3) + 8 * (reg >> 2) + 4 * l5] = s;
    }
  __syncthreads();
  if (tid < 128) {
    float v = 0.0f;
#pragma unroll
    for (int w = 0; w < 8; w++) v += part_lds[w][tid];
    partials[(size_t)px * MTOT + m0 + tid] = v;
  }
}

// --------- kernel 2: per-batch-row exact select (stable-argsort semantics) + softmax
__global__ void k_select(const float* __restrict__ partials, const float* __restrict__ b2,
                         float* __restrict__ weights)
{
  __shared__ float s_lds[TLEN];
  __shared__ unsigned long long keys[TLEN];
  __shared__ float red[20];
  const int b = blockIdx.x, tid = threadIdx.x;
  const float b2v = b2[0];

  for (int i = tid; i < TLEN; i += 1024) {
    size_t idx = (size_t)b * TLEN + i;
    float s = partials[idx] + partials[idx + (size_t)MTOT] +
              partials[idx + 2 * (size_t)MTOT] + partials[idx + 3 * (size_t)MTOT] + b2v;
    s_lds[i] = s;
    unsigned u = __float_as_uint(s);
    u = (u & 0x80000000u) ? ~u : (u | 0x80000000u);  // order-preserving float->uint
    keys[i] = ((unsigned long long)u << 32) | (unsigned)i;
  }
  __syncthreads();
  // bitonic sort ascending (key = (score, index) — matches stable argsort)
  for (int k = 2; k <= TLEN; k <<= 1)
    for (int j = k >> 1; j > 0; j >>= 1) {
      for (int i = tid; i < TLEN; i += 1024) {
        int p = i ^ j;
        if (p > i) {
          unsigned long long a = keys[i], c = keys[p];
          bool up = ((i & k) == 0);
          if ((a > c) == up) { keys[i] = c; keys[p] = a; }
        }
      }
      __syncthreads();
    }

  const unsigned long long thr = keys[NMASK];        // first KEPT pair
  unsigned um = (unsigned)(keys[TLEN - 1] >> 32);    // decode row max
  um = (um & 0x80000000u) ? (um ^ 0x80000000u) : ~um;
  const float m = __uint_as_float(um);

  float ev[4]; bool kp[4]; float zp = 0.0f;
#pragma unroll
  for (int q = 0; q < 4; q++) {
    int i = tid + q * 1024;
    float s = s_lds[i];
    unsigned u = __float_as_uint(s);
    u = (u & 0x80000000u) ? ~u : (u | 0x80000000u);
    unsigned long long key = ((unsigned long long)u << 32) | (unsigned)i;
    kp[q] = (key >= thr);
    ev[q] = __expf(s - m);
    if (kp[q]) zp += ev[q];
  }
#pragma unroll
  for (int off = 1; off < 64; off <<= 1) zp += __shfl_xor(zp, off, 64);
  if ((tid & 63) == 0) red[tid >> 6] = zp;
  __syncthreads();
  if (tid == 0) { float z = 0.0f; for (int i = 0; i < 16; i++) z += red[i]; red[16] = z; }
  __syncthreads();
  const float invZ = 1.0f / red[16];
#pragma unroll
  for (int q = 0; q < 4; q++) {
    int i = tid + q * 1024;
    weights[(size_t)b * TLEN + i] = kp[q] ? ev[q] * invZ : 0.0f;
  }
}

// --------- kernel 3: masked_output = x * weights[row] ---------
__global__ void k_scale(const float* __restrict__ x, const float* __restrict__ weights,
                        float* __restrict__ out)
{
  const size_t n4 = (size_t)MTOT * DDIM / 4;
  for (size_t f = (size_t)blockIdx.x * blockDim.x + threadIdx.x; f < n4;
       f += (size_t)gridDim.x * blockDim.x) {
    float w = weights[f >> 8];                       // 256 float4 per row
    float4v v = ((const float4v*)x)[f];
    ((float4v*)out)[f] = v * w;
  }
}

extern "C" void kernel_launch(void* const* d_in, const int* in_sizes, int n_in,
                              void* d_out, int out_size, void* d_ws, size_t ws_size,
                              hipStream_t stream)
{
  const float* x  = (const float*)d_in[0];
  const float* W1 = (const float*)d_in[1];
  const float* b1 = (const float*)d_in[2];
  const float* w2 = (const float*)d_in[3];
  const float* b2 = (const float*)d_in[4];
  float* out = (float*)d_out;
  float* weights = out + (size_t)MTOT * DDIM;        // output 1 region

  char* ws = (char*)d_ws;                            // 6 MiB total
  _Float16* Wp    = (_Float16*)ws;                   // 4 MiB
  float*    parts = (float*)(ws + (4u << 20));       // 2 MiB

  k_wpack<<<512, 256, 0, stream>>>(W1, Wp);          // 2048 frags x 4/block
  k_score<<<4096, 512, 0, stream>>>(x, Wp, b1, w2, parts);
  k_select<<<BATCH, 1024, 0, stream>>>(parts, b2, weights);
  k_scale<<<2048, 256, 0, stream>>>(x, weights, out);
}

// Round 11
// 1092.924 us; speedup vs baseline: 1.1486x; 1.0498x over previous
//
#include <hip/hip_runtime.h>

typedef _Float16 half8 __attribute__((ext_vector_type(8)));
typedef _Float16 half4v __attribute__((ext_vector_type(4)));
typedef float floatx16 __attribute__((ext_vector_type(16)));
typedef float float4v __attribute__((ext_vector_type(4)));

#define MTOT 131072   // B*T rows
#define DDIM 1024
#define TLEN 4096
#define BATCH 32
#define NMASK 2048

// --------- kernel 0: pack W1 into MFMA B-fragment order, fp16-split (x512) ----
// 2048 fragments: f = cb*64 + kb. Wp[f][hl][lane][8]: lane l -> col cb*32+(l&31),
// k kb*16+(l>>5)*8+j. B-frag load in k_score = ONE coalesced 1KB wave-load.
__global__ void k_wpack(const float* __restrict__ W1, _Float16* __restrict__ Wp)
{
  const int f = blockIdx.x * 4 + (threadIdx.x >> 6);  // 0..2047
  const int l = threadIdx.x & 63;
  const int cb = f >> 6, kb = f & 63;
  const int col = cb * 32 + (l & 31);
  const int k0 = kb * 16 + (l >> 5) * 8;
  half8 hv, lv;
#pragma unroll
  for (int j = 0; j < 8; j++) {
    float w = W1[(size_t)(k0 + j) * DDIM + col] * 512.0f;
    _Float16 h = (_Float16)w;
    hv[j] = h; lv[j] = (_Float16)(w - (float)h);
  }
  *(half8*)(Wp + ((size_t)(f * 2 + 0) * 64 + l) * 8) = hv;
  *(half8*)(Wp + ((size_t)(f * 2 + 1) * 64 + l) * 8) = lv;
}

// --------- kernel 1: fused scores GEMM ----------------------------------------
// tile 128x256, 8 waves COL-SPLIT (wave wn owns cols wn*32, all 128 rows).
// Reg-peak-aware schedule (fits 64 VGPR + 64 AGPR at launch_bounds(512,4)):
// [8 B(t) loads (32reg)][kc0,1 MFMA - B01 die][LOADX(t+1) (16reg)][kc2,3 MFMA]
// [SPLITW: vmcnt hits xv aged ~800cyc][ONE barrier]. Split fp32->hi/lo once
// per block at LDS-write; XOR-chunk layout both-sides (write (c>>1)^(r&15)).
__global__ __launch_bounds__(512, 4) void k_score(
    const float* __restrict__ x, const _Float16* __restrict__ Wp,
    const float* __restrict__ b1, const float* __restrict__ w2,
    float* __restrict__ partials)
{
  __shared__ __align__(16) _Float16 Abuf[2][128 * 128];  // 32 KB each
  __shared__ float part_lds[8][128];

  const int tid  = threadIdx.x;
  const int lane = tid & 63;
  const int wn   = tid >> 6;               // wave = col group 0..7
  const int l31 = lane & 31, l5 = lane >> 5;

  // XCD-bijective decode (proven FETCH-halving): 4 col-blocks of a row-panel
  // land on one XCD -> panel enters that L2 once.
  const int id  = blockIdx.x;
  const int xcd = id & 7, seq = id >> 3;
  const int px  = seq & 3;                 // col-block 0..3
  const int py  = (seq >> 2) * 8 + xcd;    // row-panel 0..1023
  const int m0 = py * 128;

  // A staging map: thread -> (row rr+g*32, f32-quad cc) ; coalesced 256B/16 lanes
  const int rr = tid >> 4;                 // 0..31
  const int cc = tid & 15;                 // f32-quad within 64
  const float* xs = x + (size_t)(m0 + rr) * DDIM + cc * 4;

  // B fragment base: col-group cb = px*8 + wn; frag (cb*64 + t*4 + kc)
  const _Float16* wpb = Wp + (size_t)(px * 8 + wn) * 64 * 1024 + lane * 8;

  floatx16 acc[4] = {};
  float4v xv[4];

#define LOADX(T)                                                        \
  _Pragma("unroll")                                                     \
  for (int g = 0; g < 4; g++)                                           \
    xv[g] = *(const float4v*)(xs + (size_t)g * 32 * DDIM + (T) * 64);

  // split 16 f32 -> hi/lo f16, write as 8B units into XOR'd chunk layout
#define SPLITW(BUF)                                                     \
  _Pragma("unroll")                                                     \
  for (int g = 0; g < 4; g++) {                                         \
    int r = rr + g * 32;                                                \
    int Phi = (cc >> 1) ^ (r & 15);                                     \
    half4v hv, lv;                                                      \
    _Pragma("unroll")                                                   \
    for (int i = 0; i < 4; i++) {                                       \
      _Float16 h = (_Float16)xv[g][i];                                  \
      hv[i] = h; lv[i] = (_Float16)(xv[g][i] - (float)h);               \
    }                                                                   \
    *(half4v*)&Abuf[BUF][r * 128 + Phi * 8 + (cc & 1) * 4] = hv;        \
    *(half4v*)&Abuf[BUF][r * 128 + (Phi ^ 8) * 8 + (cc & 1) * 4] = lv;  \
  }

  // one kc-slice: 2 ds_read_b128 + 12 MFMA per mf-quad
#define KCSTEP(CUR, KC)                                                 \
  _Pragma("unroll")                                                     \
  for (int mf = 0; mf < 4; mf++) {                                      \
    int r = mf * 32 + l31;                                              \
    int base = r * 128;                                                 \
    half8 ah = *(const half8*)&Abuf[CUR][base + ((((KC) * 2 + l5)    ) ^ (r & 15)) * 8]; \
    half8 al = *(const half8*)&Abuf[CUR][base + ((8 + (KC) * 2 + l5) ^ (r & 15)) * 8];   \
    acc[mf] = __builtin_amdgcn_mfma_f32_32x32x16_f16(ah, bh[KC], acc[mf], 0, 0, 0);      \
    acc[mf] = __builtin_amdgcn_mfma_f32_32x32x16_f16(ah, bl[KC], acc[mf], 0, 0, 0);      \
    acc[mf] = __builtin_amdgcn_mfma_f32_32x32x16_f16(al, bh[KC], acc[mf], 0, 0, 0);      \
  }

  // ---- prologue: tile 0 -> buf 0 ----
  LOADX(0)
  SPLITW(0)
  __syncthreads();

#pragma unroll 1
  for (int t = 0; t < 16; ++t) {
    const int cur = t & 1;
    // ---- oldest VMEM: this tile's 8 B-halves (coalesced 1KB wave-loads) ----
    half8 bh[4], bl[4];
#pragma unroll
    for (int kc = 0; kc < 4; kc++) {
      bh[kc] = *(const half8*)(wpb + (size_t)(t * 4 + kc) * 1024);
      bl[kc] = *(const half8*)(wpb + (size_t)(t * 4 + kc) * 1024 + 512);
    }
    __builtin_amdgcn_sched_barrier(0);
    __builtin_amdgcn_s_setprio(1);
    KCSTEP(cur, 0)
    KCSTEP(cur, 1)
    __builtin_amdgcn_s_setprio(0);
    __builtin_amdgcn_sched_barrier(0);
    // ---- A(t+1) -> regs, issued mid-cluster after B01 regs freed ----
    if (t < 15) LOADX(t + 1)
    __builtin_amdgcn_sched_barrier(0);
    __builtin_amdgcn_s_setprio(1);
    KCSTEP(cur, 2)
    KCSTEP(cur, 3)
    __builtin_amdgcn_s_setprio(0);
    __builtin_amdgcn_sched_barrier(0);
    // ---- split+write A(t+1): vmcnt wait hits xv aged ~2 kc-slices ----
    if (t < 15) SPLITW(cur ^ 1)
    __syncthreads();
  }
#undef LOADX
#undef SPLITW
#undef KCSTEP

  // ---- epilogue: tanh + dot(w2) + row reduce (32 cols per wave) ----
  const int col = px * 256 + wn * 32 + l31;
  const float b1v = b1[col];
  const float w2v = w2[col];
  const float inv512 = 1.0f / 512.0f;
#pragma unroll
  for (int mf = 0; mf < 4; mf++)
#pragma unroll
    for (int reg = 0; reg < 16; reg++) {
      float pre = acc[mf][reg] * inv512 + b1v;
      float a = fabsf(pre);
      float e = __expf(-2.0f * a);
      float tt = (1.0f - e) / (1.0f + e);             // tanh(|pre|)
      float s = copysignf(tt, pre) * w2v;
#pragma unroll
      for (int off = 1; off < 32; off <<= 1) s += __shfl_xor(s, off, 64);
      if (l31 == 0)
        part_lds[wn][mf * 32 + (reg & 3) + 8 * (reg >> 2) + 4 * l5] = s;
    }
  __syncthreads();
  if (tid < 128) {
    float v = 0.0f;
#pragma unroll
    for (int w = 0; w < 8; w++) v += part_lds[w][tid];
    partials[(size_t)px * MTOT + m0 + tid] = v;
  }
}

// --------- kernel 2: per-batch-row exact select (stable-argsort semantics) + softmax
__global__ void k_select(const float* __restrict__ partials, const float* __restrict__ b2,
                         float* __restrict__ weights)
{
  __shared__ float s_lds[TLEN];
  __shared__ unsigned long long keys[TLEN];
  __shared__ float red[20];
  const int b = blockIdx.x, tid = threadIdx.x;
  const float b2v = b2[0];

  for (int i = tid; i < TLEN; i += 1024) {
    size_t idx = (size_t)b * TLEN + i;
    float s = partials[idx] + partials[idx + (size_t)MTOT] +
              partials[idx + 2 * (size_t)MTOT] + partials[idx + 3 * (size_t)MTOT] + b2v;
    s_lds[i] = s;
    unsigned u = __float_as_uint(s);
    u = (u & 0x80000000u) ? ~u : (u | 0x80000000u);  // order-preserving float->uint
    keys[i] = ((unsigned long long)u << 32) | (unsigned)i;
  }
  __syncthreads();
  // bitonic sort ascending (key = (score, index) — matches stable argsort)
  for (int k = 2; k <= TLEN; k <<= 1)
    for (int j = k >> 1; j > 0; j >>= 1) {
      for (int i = tid; i < TLEN; i += 1024) {
        int p = i ^ j;
        if (p > i) {
          unsigned long long a = keys[i], c = keys[p];
          bool up = ((i & k) == 0);
          if ((a > c) == up) { keys[i] = c; keys[p] = a; }
        }
      }
      __syncthreads();
    }

  const unsigned long long thr = keys[NMASK];        // first KEPT pair
  unsigned um = (unsigned)(keys[TLEN - 1] >> 32);    // decode row max
  um = (um & 0x80000000u) ? (um ^ 0x80000000u) : ~um;
  const float m = __uint_as_float(um);

  float ev[4]; bool kp[4]; float zp = 0.0f;
#pragma unroll
  for (int q = 0; q < 4; q++) {
    int i = tid + q * 1024;
    float s = s_lds[i];
    unsigned u = __float_as_uint(s);
    u = (u & 0x80000000u) ? ~u : (u | 0x80000000u);
    unsigned long long key = ((unsigned long long)u << 32) | (unsigned)i;
    kp[q] = (key >= thr);
    ev[q] = __expf(s - m);
    if (kp[q]) zp += ev[q];
  }
#pragma unroll
  for (int off = 1; off < 64; off <<= 1) zp += __shfl_xor(zp, off, 64);
  if ((tid & 63) == 0) red[tid >> 6] = zp;
  __syncthreads();
  if (tid == 0) { float z = 0.0f; for (int i = 0; i < 16; i++) z += red[i]; red[16] = z; }
  __syncthreads();
  const float invZ = 1.0f / red[16];
#pragma unroll
  for (int q = 0; q < 4; q++) {
    int i = tid + q * 1024;
    weights[(size_t)b * TLEN + i] = kp[q] ? ev[q] * invZ : 0.0f;
  }
}

// --------- kernel 3: masked_output = x * weights[row] ---------
__global__ void k_scale(const float* __restrict__ x, const float* __restrict__ weights,
                        float* __restrict__ out)
{
  const size_t n4 = (size_t)MTOT * DDIM / 4;
  for (size_t f = (size_t)blockIdx.x * blockDim.x + threadIdx.x; f < n4;
       f += (size_t)gridDim.x * blockDim.x) {
    float w = weights[f >> 8];                       // 256 float4 per row
    float4v v = ((const float4v*)x)[f];
    ((float4v*)out)[f] = v * w;
  }
}

extern "C" void kernel_launch(void* const* d_in, const int* in_sizes, int n_in,
                              void* d_out, int out_size, void* d_ws, size_t ws_size,
                              hipStream_t stream)
{
  const float* x  = (const float*)d_in[0];
  const float* W1 = (const float*)d_in[1];
  const float* b1 = (const float*)d_in[2];
  const float* w2 = (const float*)d_in[3];
  const float* b2 = (const float*)d_in[4];
  float* out = (float*)d_out;
  float* weights = out + (size_t)MTOT * DDIM;        // output 1 region

  char* ws = (char*)d_ws;                            // 6 MiB total
  _Float16* Wp    = (_Float16*)ws;                   // 4 MiB
  float*    parts = (float*)(ws + (4u << 20));       // 2 MiB

  k_wpack<<<512, 256, 0, stream>>>(W1, Wp);          // 2048 frags x 4/block
  k_score<<<4096, 512, 0, stream>>>(x, Wp, b1, w2, parts);
  k_select<<<BATCH, 1024, 0, stream>>>(parts, b2, weights);
  k_scale<<<2048, 256, 0, stream>>>(x, weights, out);
}